// Round 1
// 597.446 us; speedup vs baseline: 1.0064x; 1.0064x over previous
//
#include <hip/hip_runtime.h>
#include <hip/hip_bf16.h>

// GCN 2-layer forward. CSR pull-aggregation (one node per lane-group).
// GEMMs are BARRIER-FREE and LDS-FREE: per-wave row ownership, A register-
// prefetch distance 2, B fragments read directly from L2-resident packed
// weights. Rounds 6-8 proved any per-step __syncthreads drains vmcnt(0) and
// defeats every software pipeline (m97-plateau); the fix is no barriers.
// This round: int4-batched col loads + col prefetch in both agg kernels,
// packW merged into count_deg, single-block scan_bsums eliminated
// (per-block bsums prefix reduction), shfl-based scan. 11 -> 9 dispatches.
// N=100000, F_IN=512, HID=128, C=40, E=1.6M

#define F_IN 512
#define HID  128
#define NC   40

typedef __attribute__((ext_vector_type(8))) short bf16x8;
typedef __attribute__((ext_vector_type(4))) float f32x4v;

__device__ __forceinline__ ushort f2bf(float f) {
    union { float f; unsigned u; } x; x.f = f;
    unsigned r = x.u + 0x7FFFu + ((x.u >> 16) & 1u);   // round-to-nearest-even
    return (ushort)(r >> 16);
}
__device__ __forceinline__ float bf2f(ushort u) {
    return __uint_as_float((unsigned)u << 16);
}
__device__ __forceinline__ bf16x8 cvt8(float4 lo, float4 hi) {
    __align__(16) ushort t[8];
    t[0]=f2bf(lo.x); t[1]=f2bf(lo.y); t[2]=f2bf(lo.z); t[3]=f2bf(lo.w);
    t[4]=f2bf(hi.x); t[5]=f2bf(hi.y); t[6]=f2bf(hi.z); t[7]=f2bf(hi.w);
    return *(const bf16x8*)t;
}

// ---------------- degree count (real edges) + weight pack, one launch -------
// Blocks [0, EB): per-edge atomic degree count.
// Blocks [EB, EB+280): pack W1 -> W1p bf16 and W2 -> W2p bf16 (padded).
// W1p: [s(16)][kb(4)][n(128)][j(8)], k = s*32+kb*8+j   (65536 elems)
// W2p: [ks(4)][kb(4)][n(48)][j(8)],  k = ks*32+kb*8+j  (6144 elems, n>=40 -> 0)
__global__ void prep_k(const int* __restrict__ dst, int E, int EB,
                       unsigned* __restrict__ cnt,
                       const float* __restrict__ W1, const float* __restrict__ W2,
                       ushort* __restrict__ W1p, ushort* __restrict__ W2p) {
    int b = blockIdx.x;
    if (b < EB) {
        int t = b * 256 + threadIdx.x;
        if (t < E) atomicAdd(&cnt[dst[t]], 1u);
        return;
    }
    int t = (b - EB) * 256 + threadIdx.x;
    if (t < 65536) {
        int j = t & 7, n = (t >> 3) & 127, kb = (t >> 10) & 3, s = t >> 12;
        int k = s * 32 + kb * 8 + j;
        W1p[t] = f2bf(W1[(size_t)k * HID + n]);
    } else {
        int q = t - 65536;
        if (q < 6144) {
            int j = q & 7;
            int i2 = q >> 3;
            int n = i2 % 48;
            int i3 = i2 / 48;
            int kb = i3 & 3, ks = i3 >> 2;
            int k = ks * 32 + kb * 8 + j;
            float v = (n < NC) ? W2[(size_t)k * NC + n] : 0.f;
            W2p[q] = f2bf(v);
        }
    }
}

// ---------------- block-local exclusive scan (shfl-based) + fused dis -------
__global__ __launch_bounds__(1024) void scan_block(const unsigned* __restrict__ cnt,
                                                   unsigned* __restrict__ offs,
                                                   unsigned* __restrict__ bsums,
                                                   float* __restrict__ dis, int N) {
    int tid = threadIdx.x;
    int i = blockIdx.x * 1024 + tid;
    unsigned v = (i < N) ? cnt[i] : 0u;
    if (i < N) dis[i] = rsqrtf((float)v + 1.0f);   // +1 = self loop
    int lane = tid & 63, w = tid >> 6;
    unsigned s = v;
    #pragma unroll
    for (int d = 1; d < 64; d <<= 1) {
        unsigned t = __shfl_up(s, d, 64);
        if (lane >= d) s += t;
    }
    __shared__ unsigned wt[16];
    if (lane == 63) wt[w] = s;
    __syncthreads();
    unsigned add = 0;
    #pragma unroll
    for (int j = 0; j < 16; j++) add += (j < w) ? wt[j] : 0u;
    unsigned incl = s + add;
    if (i < N) offs[i] = incl - v;                 // exclusive within block
    if (tid == 1023) bsums[blockIdx.x] = incl;     // raw block total
}

// ---------------- add bsums prefix (computed in-block, no serial kernel) ----
__global__ __launch_bounds__(1024) void scan_add2(unsigned* __restrict__ offs,
                                                  const unsigned* __restrict__ bsums,
                                                  int N, unsigned total) {
    int i = blockIdx.x * 1024 + threadIdx.x;
    int lane = threadIdx.x & 63;
    unsigned s = 0;
    for (int j = lane; j < (int)blockIdx.x; j += 64) s += bsums[j];
    #pragma unroll
    for (int d = 1; d < 64; d <<= 1) s += __shfl_xor(s, d, 64);
    if (i < N) offs[i] += s;
    if (i == 0) offs[N] = total;
}

// ---------------- CSR fill (real edges only) ----------------
__global__ void fill_csr(const int* __restrict__ src, const int* __restrict__ dst,
                         const unsigned* __restrict__ offs, unsigned* __restrict__ cursor,
                         int* __restrict__ col, int E) {
    int t = blockIdx.x * blockDim.x + threadIdx.x;
    if (t >= E) return;
    int s = src[t], d = dst[t];
    unsigned pos = offs[d] + atomicAdd(&cursor[d], 1u);
    col[pos] = s;
}

// ------- GEMM1 MFMA, barrier-free: h1s[N,128] = (bf16(x) @ W1) * dis[row] ---
__global__ __launch_bounds__(256) void gemm1_mfma(const float* __restrict__ A,
                                                  const ushort* __restrict__ Bp,
                                                  const float* __restrict__ dis,
                                                  ushort* __restrict__ C, int N) {
    const int tid  = threadIdx.x;
    const int wave = tid >> 6;
    const int lane = tid & 63;
    const int quad = lane >> 4;
    const int mr   = lane & 15;
    const int base = (blockIdx.x * 4 + wave) * 32;
    if (base >= N) return;
    const int r0 = base + mr;
    const int r1 = base + 16 + mr;
    const bool ok0 = r0 < N, ok1 = r1 < N;
    const float* ap0 = A + (size_t)(ok0 ? r0 : 0) * F_IN + quad * 8;
    const float* ap1 = A + (size_t)(ok1 ? r1 : 0) * F_IN + quad * 8;
    const ushort* bp = Bp + quad * 1024 + mr * 8;   // + s*4096 + t*128

    f32x4v acc0[8], acc1[8];
    #pragma unroll
    for (int t = 0; t < 8; t++) {
        acc0[t] = (f32x4v){0.f, 0.f, 0.f, 0.f};
        acc1[t] = (f32x4v){0.f, 0.f, 0.f, 0.f};
    }

    // A prefetch regs: [buf][r0lo, r0hi, r1lo, r1hi]
    float4 av[2][4];
    #pragma unroll
    for (int b = 0; b < 2; b++) {
        av[b][0] = *(const float4*)(ap0 + b * 32);
        av[b][1] = *(const float4*)(ap0 + b * 32 + 4);
        av[b][2] = *(const float4*)(ap1 + b * 32);
        av[b][3] = *(const float4*)(ap1 + b * 32 + 4);
    }

    for (int s = 0; s < 16; s++) {
        bf16x8 fa0 = cvt8(av[s & 1][0], av[s & 1][1]);
        bf16x8 fa1 = cvt8(av[s & 1][2], av[s & 1][3]);
        if (s < 14) {   // reload this buffer with step s+2 (distance 2)
            av[s & 1][0] = *(const float4*)(ap0 + (s + 2) * 32);
            av[s & 1][1] = *(const float4*)(ap0 + (s + 2) * 32 + 4);
            av[s & 1][2] = *(const float4*)(ap1 + (s + 2) * 32);
            av[s & 1][3] = *(const float4*)(ap1 + (s + 2) * 32 + 4);
        }
        const ushort* bs = bp + s * 4096;
        #pragma unroll
        for (int t = 0; t < 8; t++) {
            bf16x8 b = *(const bf16x8*)(bs + t * 128);
            acc0[t] = __builtin_amdgcn_mfma_f32_16x16x32_bf16(fa0, b, acc0[t], 0, 0, 0);
            acc1[t] = __builtin_amdgcn_mfma_f32_16x16x32_bf16(fa1, b, acc1[t], 0, 0, 0);
        }
    }

    // epilogue: C/D layout col=t*16+mr, row=quad*4+rr; scale by dis[row]
    #pragma unroll
    for (int rr = 0; rr < 4; rr++) {
        int ra = base + quad * 4 + rr;
        if (ra < N) {
            float ds = dis[ra];
            #pragma unroll
            for (int t = 0; t < 8; t++)
                C[(size_t)ra * HID + t * 16 + mr] = f2bf(acc0[t][rr] * ds);
        }
        int rb = base + 16 + quad * 4 + rr;
        if (rb < N) {
            float ds = dis[rb];
            #pragma unroll
            for (int t = 0; t < 8; t++)
                C[(size_t)rb * HID + t * 16 + mr] = f2bf(acc1[t][rr] * ds);
        }
    }
}

// ------- agg1: one node per 16-lane group, int4 col batches + prefetch ------
// out[node] = bf16( relu( dis[node] * (h1s[node] + sum h1s[s]) + b1 ) )
__global__ __launch_bounds__(256) void agg1_k(const ushort* __restrict__ h,
                                              const int* __restrict__ col,
                                              const unsigned* __restrict__ offs,
                                              const float* __restrict__ dis,
                                              const float* __restrict__ b1,
                                              ushort* __restrict__ out, int N) {
    int node = blockIdx.x * 16 + (threadIdx.x >> 4);
    if (node >= N) return;
    int lane = threadIdx.x & 15;
    const ushort* hb = h + (size_t)lane * 8;
    float a[8];
    {   // self
        uint4 v = *(const uint4*)(hb + (size_t)node * HID);
        const ushort* u = (const ushort*)&v;
        #pragma unroll
        for (int j = 0; j < 8; j++) a[j] = bf2f(u[j]);
    }
    unsigned p0 = offs[node], p1 = offs[node + 1];
    unsigned p = p0;
    // head peel to 16B-aligned col pointer
    while (p < p1 && (p & 3u)) {
        int s = col[p++];
        uint4 v = *(const uint4*)(hb + (size_t)s * HID);
        const ushort* u = (const ushort*)&v;
        #pragma unroll
        for (int j = 0; j < 8; j++) a[j] += bf2f(u[j]);
    }
    unsigned rem = p1 - p;
    const int4* cp = (const int4*)(col + p);
    unsigned nb8 = rem >> 3;
    int4 c0, c1;
    if (nb8) { c0 = cp[0]; c1 = cp[1]; }
    for (unsigned b = 0; b < nb8; b++) {
        uint4 v0 = *(const uint4*)(hb + (size_t)c0.x * HID);
        uint4 v1 = *(const uint4*)(hb + (size_t)c0.y * HID);
        uint4 v2 = *(const uint4*)(hb + (size_t)c0.z * HID);
        uint4 v3 = *(const uint4*)(hb + (size_t)c0.w * HID);
        uint4 v4 = *(const uint4*)(hb + (size_t)c1.x * HID);
        uint4 v5 = *(const uint4*)(hb + (size_t)c1.y * HID);
        uint4 v6 = *(const uint4*)(hb + (size_t)c1.z * HID);
        uint4 v7 = *(const uint4*)(hb + (size_t)c1.w * HID);
        if (b + 1 < nb8) { c0 = cp[2 * b + 2]; c1 = cp[2 * b + 3]; }  // prefetch
        const ushort* u0 = (const ushort*)&v0;
        const ushort* u1 = (const ushort*)&v1;
        const ushort* u2 = (const ushort*)&v2;
        const ushort* u3 = (const ushort*)&v3;
        const ushort* u4 = (const ushort*)&v4;
        const ushort* u5 = (const ushort*)&v5;
        const ushort* u6 = (const ushort*)&v6;
        const ushort* u7 = (const ushort*)&v7;
        #pragma unroll
        for (int j = 0; j < 8; j++) {
            float t0 = bf2f(u0[j]) + bf2f(u1[j]);
            float t1 = bf2f(u2[j]) + bf2f(u3[j]);
            float t2 = bf2f(u4[j]) + bf2f(u5[j]);
            float t3 = bf2f(u6[j]) + bf2f(u7[j]);
            a[j] += (t0 + t1) + (t2 + t3);
        }
    }
    p += nb8 << 3;
    if (rem & 4u) {
        int4 c = *(const int4*)(col + p);
        uint4 v0 = *(const uint4*)(hb + (size_t)c.x * HID);
        uint4 v1 = *(const uint4*)(hb + (size_t)c.y * HID);
        uint4 v2 = *(const uint4*)(hb + (size_t)c.z * HID);
        uint4 v3 = *(const uint4*)(hb + (size_t)c.w * HID);
        const ushort* u0 = (const ushort*)&v0;
        const ushort* u1 = (const ushort*)&v1;
        const ushort* u2 = (const ushort*)&v2;
        const ushort* u3 = (const ushort*)&v3;
        #pragma unroll
        for (int j = 0; j < 8; j++)
            a[j] += (bf2f(u0[j]) + bf2f(u1[j])) + (bf2f(u2[j]) + bf2f(u3[j]));
        p += 4;
    }
    for (; p < p1; ++p) {
        int s = col[p];
        uint4 v = *(const uint4*)(hb + (size_t)s * HID);
        const ushort* u = (const ushort*)&v;
        #pragma unroll
        for (int j = 0; j < 8; j++) a[j] += bf2f(u[j]);
    }
    float dd = dis[node];
    float4 bb0 = *(const float4*)(b1 + lane * 8);
    float4 bb1 = *(const float4*)(b1 + lane * 8 + 4);
    const float bb[8] = {bb0.x, bb0.y, bb0.z, bb0.w, bb1.x, bb1.y, bb1.z, bb1.w};
    __align__(16) ushort o[8];
    #pragma unroll
    for (int j = 0; j < 8; j++) o[j] = f2bf(fmaxf(a[j] * dd + bb[j], 0.f));
    *(uint4*)(out + (size_t)node * HID + (size_t)lane * 8) = *(const uint4*)o;
}

// ------- GEMM2 MFMA, barrier-free: h2s[N,40] = (ag1 @ W2) * dis[row] (bf16) -
__global__ __launch_bounds__(256) void gemm2_mfma(const ushort* __restrict__ A,
                                                  const ushort* __restrict__ W2p,
                                                  const float* __restrict__ dis,
                                                  ushort* __restrict__ h2, int N) {
    const int tid  = threadIdx.x;
    const int wave = tid >> 6;
    const int lane = tid & 63;
    const int quad = lane >> 4;
    const int mr   = lane & 15;
    const int base = (blockIdx.x * 4 + wave) * 32;
    if (base >= N) return;
    const int r0 = base + mr;
    const int r1 = base + 16 + mr;
    const bool ok0 = r0 < N, ok1 = r1 < N;
    const ushort* ap0 = A + (size_t)(ok0 ? r0 : 0) * HID + quad * 8;
    const ushort* ap1 = A + (size_t)(ok1 ? r1 : 0) * HID + quad * 8;
    const ushort* bp = W2p + quad * 384 + mr * 8;   // + ks*1536 + t*128

    f32x4v acc0[3], acc1[3];
    #pragma unroll
    for (int t = 0; t < 3; t++) {
        acc0[t] = (f32x4v){0.f, 0.f, 0.f, 0.f};
        acc1[t] = (f32x4v){0.f, 0.f, 0.f, 0.f};
    }
    #pragma unroll
    for (int ks = 0; ks < 4; ks++) {
        bf16x8 a0 = *(const bf16x8*)(ap0 + ks * 32);
        bf16x8 a1 = *(const bf16x8*)(ap1 + ks * 32);
        #pragma unroll
        for (int t = 0; t < 3; t++) {
            bf16x8 b = *(const bf16x8*)(bp + ks * 1536 + t * 128);
            acc0[t] = __builtin_amdgcn_mfma_f32_16x16x32_bf16(a0, b, acc0[t], 0, 0, 0);
            acc1[t] = __builtin_amdgcn_mfma_f32_16x16x32_bf16(a1, b, acc1[t], 0, 0, 0);
        }
    }
    #pragma unroll
    for (int rr = 0; rr < 4; rr++) {
        int ra = base + quad * 4 + rr;
        if (ra < N) {
            float ds = dis[ra];
            #pragma unroll
            for (int t = 0; t < 3; t++) {
                int c = t * 16 + mr;
                if (c < NC) h2[(size_t)ra * NC + c] = f2bf(acc0[t][rr] * ds);
            }
        }
        int rb = base + 16 + quad * 4 + rr;
        if (rb < N) {
            float ds = dis[rb];
            #pragma unroll
            for (int t = 0; t < 3; t++) {
                int c = t * 16 + mr;
                if (c < NC) h2[(size_t)rb * NC + c] = f2bf(acc1[t][rr] * ds);
            }
        }
    }
}

// ------- agg2 + b2 + log_softmax: one node per 8-lane group, 5 active lanes --
// logits = dis[node] * (h2s[node] + sum h2s[s]) + b2
__global__ __launch_bounds__(256) void agg2_ls(const ushort* __restrict__ h2,
                                               const int* __restrict__ col,
                                               const unsigned* __restrict__ offs,
                                               const float* __restrict__ dis,
                                               const float* __restrict__ b2,
                                               float* __restrict__ out, int N) {
    int node = blockIdx.x * 32 + (threadIdx.x >> 3);
    if (node >= N) return;
    int lane = threadIdx.x & 7;
    const bool act = lane < 5;
    const ushort* hb = h2 + (size_t)lane * 8;
    float a[8] = {};
    if (act) {
        uint4 v = *(const uint4*)(hb + (size_t)node * NC);
        const ushort* u = (const ushort*)&v;
        #pragma unroll
        for (int j = 0; j < 8; j++) a[j] = bf2f(u[j]);
    }
    unsigned p0 = offs[node], p1 = offs[node + 1];
    unsigned p = p0;
    while (p < p1 && (p & 3u)) {
        int s = col[p++];
        if (act) {
            uint4 v = *(const uint4*)(hb + (size_t)s * NC);
            const ushort* u = (const ushort*)&v;
            #pragma unroll
            for (int j = 0; j < 8; j++) a[j] += bf2f(u[j]);
        }
    }
    unsigned rem = p1 - p;
    const int4* cp = (const int4*)(col + p);
    unsigned nb8 = rem >> 3;
    int4 c0, c1;
    if (nb8) { c0 = cp[0]; c1 = cp[1]; }
    for (unsigned b = 0; b < nb8; b++) {
        int s0 = c0.x, s1 = c0.y, s2 = c0.z, s3 = c0.w;
        int s4 = c1.x, s5 = c1.y, s6 = c1.z, s7 = c1.w;
        if (b + 1 < nb8) { c0 = cp[2 * b + 2]; c1 = cp[2 * b + 3]; }  // prefetch
        if (act) {
            uint4 v0 = *(const uint4*)(hb + (size_t)s0 * NC);
            uint4 v1 = *(const uint4*)(hb + (size_t)s1 * NC);
            uint4 v2 = *(const uint4*)(hb + (size_t)s2 * NC);
            uint4 v3 = *(const uint4*)(hb + (size_t)s3 * NC);
            uint4 v4 = *(const uint4*)(hb + (size_t)s4 * NC);
            uint4 v5 = *(const uint4*)(hb + (size_t)s5 * NC);
            uint4 v6 = *(const uint4*)(hb + (size_t)s6 * NC);
            uint4 v7 = *(const uint4*)(hb + (size_t)s7 * NC);
            const ushort* u0 = (const ushort*)&v0;
            const ushort* u1 = (const ushort*)&v1;
            const ushort* u2 = (const ushort*)&v2;
            const ushort* u3 = (const ushort*)&v3;
            const ushort* u4 = (const ushort*)&v4;
            const ushort* u5 = (const ushort*)&v5;
            const ushort* u6 = (const ushort*)&v6;
            const ushort* u7 = (const ushort*)&v7;
            #pragma unroll
            for (int j = 0; j < 8; j++) {
                float t0 = bf2f(u0[j]) + bf2f(u1[j]);
                float t1 = bf2f(u2[j]) + bf2f(u3[j]);
                float t2 = bf2f(u4[j]) + bf2f(u5[j]);
                float t3 = bf2f(u6[j]) + bf2f(u7[j]);
                a[j] += (t0 + t1) + (t2 + t3);
            }
        }
    }
    p += nb8 << 3;
    if (rem & 4u) {
        int4 c = *(const int4*)(col + p);
        if (act) {
            uint4 v0 = *(const uint4*)(hb + (size_t)c.x * NC);
            uint4 v1 = *(const uint4*)(hb + (size_t)c.y * NC);
            uint4 v2 = *(const uint4*)(hb + (size_t)c.z * NC);
            uint4 v3 = *(const uint4*)(hb + (size_t)c.w * NC);
            const ushort* u0 = (const ushort*)&v0;
            const ushort* u1 = (const ushort*)&v1;
            const ushort* u2 = (const ushort*)&v2;
            const ushort* u3 = (const ushort*)&v3;
            #pragma unroll
            for (int j = 0; j < 8; j++)
                a[j] += (bf2f(u0[j]) + bf2f(u1[j])) + (bf2f(u2[j]) + bf2f(u3[j]));
        }
        p += 4;
    }
    for (; p < p1; ++p) {
        int s = col[p];
        if (act) {
            uint4 v = *(const uint4*)(hb + (size_t)s * NC);
            const ushort* u = (const ushort*)&v;
            #pragma unroll
            for (int j = 0; j < 8; j++) a[j] += bf2f(u[j]);
        }
    }
    float dd = dis[node];
    float l[8];
    float m = -1e30f;
    if (act) {
        #pragma unroll
        for (int j = 0; j < 8; j++) {
            l[j] = a[j] * dd + b2[lane * 8 + j];
            m = fmaxf(m, l[j]);
        }
    }
    #pragma unroll
    for (int d = 1; d < 8; d <<= 1) m = fmaxf(m, __shfl_xor(m, d, 8));
    float s = 0.f;
    if (act) {
        #pragma unroll
        for (int j = 0; j < 8; j++) s += __expf(l[j] - m);
    }
    #pragma unroll
    for (int d = 1; d < 8; d <<= 1) s += __shfl_xor(s, d, 8);
    float lse = m + __logf(s);
    if (act) {
        float* op = out + (size_t)node * NC + lane * 8;
        *(float4*)op       = make_float4(l[0]-lse, l[1]-lse, l[2]-lse, l[3]-lse);
        *(float4*)(op + 4) = make_float4(l[4]-lse, l[5]-lse, l[6]-lse, l[7]-lse);
    }
}

extern "C" void kernel_launch(void* const* d_in, const int* in_sizes, int n_in,
                              void* d_out, int out_size, void* d_ws, size_t ws_size,
                              hipStream_t stream) {
    const float* x  = (const float*)d_in[0];
    const int*   ei = (const int*)d_in[1];
    const float* W1 = (const float*)d_in[2];
    const float* b1 = (const float*)d_in[3];
    const float* W2 = (const float*)d_in[4];
    const float* b2 = (const float*)d_in[5];
    float* out = (float*)d_out;

    const int N = in_sizes[0] / F_IN;     // 100000
    const int E = in_sizes[1] / 2;        // 1600000
    const int* src = ei;
    const int* dst = ei + E;

    // ---- workspace layout ----
    char* ws = (char*)d_ws;
    size_t o = 0;
    unsigned* cnt  = (unsigned*)(ws + o); o += (size_t)N * 4;
    unsigned* cur  = (unsigned*)(ws + o); o += (size_t)N * 4;   // contiguous w/ cnt
    float*    dis  = (float*)   (ws + o); o += (size_t)N * 4;
    unsigned* offs = (unsigned*)(ws + o); o += (size_t)(N + 4) * 4;
    unsigned* bsums= (unsigned*)(ws + o); o += 4096;
    int*      col  = (int*)     (ws + o); o += (size_t)E * 4;
    o = (o + 15) & ~(size_t)15;
    ushort*   W1p  = (ushort*)  (ws + o); o += (size_t)F_IN * HID * 2;   // 128 KB
    o = (o + 15) & ~(size_t)15;
    ushort*   W2p  = (ushort*)  (ws + o); o += 6144 * 2;                 // 12 KB
    o = (o + 15) & ~(size_t)15;
    ushort*   h1   = (ushort*)  (ws + o); o += (size_t)N * HID * 2;      // 25.6 MB
    o = (o + 15) & ~(size_t)15;
    ushort*   ag1  = (ushort*)  (ws + o); o += (size_t)N * HID * 2;      // 25.6 MB
    o = (o + 15) & ~(size_t)15;
    ushort*   h2   = (ushort*)  (ws + o); o += (size_t)N * NC * 2;       // 8 MB

    const int nb = (N + 1023) / 1024;
    const int EB = (E + 255) / 256;
    const int PB = (65536 + 6144 + 255) / 256;   // 280 pack blocks

    // degree + weight pack in one launch (cnt and cur zeroed in one memset)
    hipMemsetAsync(cnt, 0, (size_t)N * 8, stream);
    prep_k<<<EB + PB, 256, 0, stream>>>(dst, E, EB, cnt, W1, W2, W1p, W2p);
    scan_block<<<nb, 1024, 0, stream>>>(cnt, offs, bsums, dis, N);
    scan_add2<<<nb, 1024, 0, stream>>>(offs, bsums, N, (unsigned)E);
    fill_csr<<<(E + 255) / 256, 256, 0, stream>>>(src, dst, offs, cur, col, E);

    // layer 1 (128 rows per 256-thread block: 4 waves x 32 rows)
    gemm1_mfma<<<(N + 127) / 128, 256, 0, stream>>>(x, W1p, dis, h1, N);
    agg1_k<<<(N + 15) / 16, 256, 0, stream>>>(h1, col, offs, dis, b1, ag1, N);

    // layer 2
    gemm2_mfma<<<(N + 127) / 128, 256, 0, stream>>>(ag1, W2p, dis, h2, N);
    agg2_ls<<<(N + 31) / 32, 256, 0, stream>>>(h2, col, offs, dis, b2, out, N);
}